// Round 8
// baseline (91.704 us; speedup 1.0000x reference)
//
#include <hip/hip_runtime.h>

#define NBATCH 16384
#define H 16
#define E 64
#define NB 4            // batches per wave
#define NWAVE 4         // waves per block
#define NBLK (NBATCH / (NB * NWAVE))   // 1024 blocks

// Cross-lane-through-LDS phase fence: drain LDS pipe, then stop the
// scheduler from hoisting later ops above it (rule #18). Per-wave (asm),
// NOT a block barrier.
#define LGKM0 do { asm volatile("s_waitcnt lgkmcnt(0)" ::: "memory"); \
                   __builtin_amdgcn_sched_barrier(0); } while (0)

// 4 waves/block; each wave owns a private LDS tile pair and processes NB
// batches. W (16KB fp32) is staged in LDS once per block and read with a
// 2-way-max bank pattern (free), replacing 64 L2-latency global loads per
// batch per wave (the R7 serializer). 3 blocks/CU (50KB LDS) = 12 waves/CU.
// Inputs go global->reg (transient)->padded LDS: proven spill-free at ~68
// VGPR. Score in registers, quad-shuffle softmax, attnT float4 overlay.
__global__ __launch_bounds__(256, 3) void ovo_kernel(
    const float* __restrict__ o0, const float* __restrict__ o1,
    const float* __restrict__ o2, const float* __restrict__ o3,
    const float* __restrict__ mn, const float* __restrict__ W,
    float* __restrict__ ctx_out, float* __restrict__ attn_out)
{
    __shared__ float sW[E * E];           // 16KB, block-shared, read-only
    __shared__ float sT[NWAVE][2][H * 68]; // per-wave: [0]=sA, [1]=sMain

    const int tid = threadIdx.x;
    const int l   = tid & 63;
    const int wv  = tid >> 6;

    // ---- Stage W once per block (coalesced float4; 16 floats/thread)
#pragma unroll
    for (int c = 0; c < 4; ++c) {
        const int idx = c * 1024 + tid * 4;
        *(float4*)&sW[idx] = *(const float4*)&W[idx];
    }
    __syncthreads();   // once per block; no prefetch outstanding yet

    float* const sA    = &sT[wv][0][0];   // mean -> mW -> attnT overlay
    float* const sMain = &sT[wv][1][0];   // main rows, stride 68

#pragma unroll 1
    for (int it = 0; it < NB; ++it) {
        const int batch = it * (NBLK * NWAVE) + blockIdx.x * NWAVE + wv;
        const size_t base = (size_t)batch * (H * E);

        // ---- Issue all 20 input loads (1KB coalesced each); transient regs.
        float4 ra[4], rb[4], rc[4], rd[4], rv[4];
#pragma unroll
        for (int k = 0; k < 4; ++k) {
            const int off = k * 256 + l * 4;
            ra[k] = *(const float4*)(o0 + base + off);
            rb[k] = *(const float4*)(o1 + base + off);
            rc[k] = *(const float4*)(o2 + base + off);
            rd[k] = *(const float4*)(o3 + base + off);
            rv[k] = *(const float4*)(mn + base + off);
        }

        // ---- Phase 1: mean -> sA, main -> sMain
#pragma unroll
        for (int k = 0; k < 4; ++k) {
            const int flat = k * 256 + l * 4;
            const int h = flat >> 6, e = flat & 63;
            float4 m4;
            m4.x = (ra[k].x + rb[k].x + rc[k].x + rd[k].x) * 0.25f;
            m4.y = (ra[k].y + rb[k].y + rc[k].y + rd[k].y) * 0.25f;
            m4.z = (ra[k].z + rb[k].z + rc[k].z + rd[k].z) * 0.25f;
            m4.w = (ra[k].w + rb[k].w + rc[k].w + rd[k].w) * 0.25f;
            *(float4*)&sA[h * 68 + e] = m4;
            *(float4*)&sMain[h * 68 + e] = rv[k];
        }
        LGKM0;

        // ---- Phase 2: mW[h][f] = sum_e mean[h][e]*sW[e][f]  (4x4 tile/lane),
        //      then overlay mW into sA (mean dead after the reads).
        {
            const int ht = l >> 4, ft = l & 15;
            const int h0 = ht * 4, f0 = ft * 4;
            float acc[4][4] = {{0.f}};
#pragma unroll
            for (int e0 = 0; e0 < 64; e0 += 4) {
                float4 mrow[4], wrow[4];
#pragma unroll
                for (int i = 0; i < 4; ++i) mrow[i] = *(const float4*)&sA[(h0 + i) * 68 + e0];
#pragma unroll
                for (int j = 0; j < 4; ++j) wrow[j] = *(const float4*)&sW[(e0 + j) * 64 + f0];
#pragma unroll
                for (int i = 0; i < 4; ++i) {
                    const float* mr = (const float*)&mrow[i];
#pragma unroll
                    for (int ee = 0; ee < 4; ++ee) {
                        const float* wr = (const float*)&wrow[ee];
#pragma unroll
                        for (int j = 0; j < 4; ++j)
                            acc[i][j] = fmaf(mr[ee], wr[j], acc[i][j]);
                    }
                }
            }
            LGKM0;   // this wave's mean reads retired before overlay writes
#pragma unroll
            for (int i = 0; i < 4; ++i)
                *(float4*)&sA[(h0 + i) * 68 + f0] =
                    make_float4(acc[i][0], acc[i][1], acc[i][2], acc[i][3]);
        }
        LGKM0;

        // ---- Phase 3: score[hp][g0..g0+3] in REGISTERS. lane = hp*4+gp.
        const int hp = l >> 2, gp = l & 3;
        const int g0 = gp * 4;
        float scr[4] = {0.f, 0.f, 0.f, 0.f};
#pragma unroll
        for (int f0 = 0; f0 < 64; f0 += 4) {
            float4 a0 = *(const float4*)&sA[hp * 68 + f0];      // bcast x4
            const float* pa = (const float*)&a0;
            float4 b[4];
#pragma unroll
            for (int j = 0; j < 4; ++j)
                b[j] = *(const float4*)&sMain[(g0 + j) * 68 + f0];  // bcast x16
#pragma unroll
            for (int j = 0; j < 4; ++j) {
                const float* pb = (const float*)&b[j];
#pragma unroll
                for (int q = 0; q < 4; ++q)
                    scr[j] = fmaf(pa[q], pb[q], scr[j]);
            }
        }
        LGKM0;   // mW/main reads retired before attnT overlay writes

        // ---- Phase 4: quad softmax over row hp (4 gp lanes x 4 values)
        {
            float mx = fmaxf(fmaxf(scr[0], scr[1]), fmaxf(scr[2], scr[3]));
            mx = fmaxf(mx, __shfl_xor(mx, 1));
            mx = fmaxf(mx, __shfl_xor(mx, 2));
            float e0 = __expf(scr[0] - mx), e1 = __expf(scr[1] - mx);
            float e2 = __expf(scr[2] - mx), e3 = __expf(scr[3] - mx);
            float sum = (e0 + e1) + (e2 + e3);
            sum += __shfl_xor(sum, 1);
            sum += __shfl_xor(sum, 2);
            const float inv = 1.0f / sum;
            float4 a4 = make_float4(e0 * inv, e1 * inv, e2 * inv, e3 * inv);
            // coalesced 1KB attn store: lane l covers bytes [16l,16l+16)
            *(float4*)(attn_out + (size_t)batch * (H * H) + l * 4) = a4;
            // attn^T into sA overlay (stride 20): 2-way banks max
            const float* pa4 = (const float*)&a4;
#pragma unroll
            for (int j = 0; j < 4; ++j)
                sA[(g0 + j) * 20 + hp] = pa4[j];
        }
        LGKM0;

        // ---- Phase 5: context[h][e] = sum_g attn[h][g]*main[g][e].
        //      attnT rows as float4 (16B-aligned; 4 chunks x16 bcast: free).
        {
            const int ht = l >> 4, et = l & 15;
            const int h0 = ht * 4, e0c = et * 4;
            float acc[4][4] = {{0.f}};
#pragma unroll
            for (int g = 0; g < 16; ++g) {
                float4 bv = *(const float4*)&sMain[g * 68 + e0c];
                float4 av = *(const float4*)&sA[g * 20 + h0];   // attnT[g][h0..3]
                const float* pb = (const float*)&bv;
                const float* pa = (const float*)&av;
#pragma unroll
                for (int i = 0; i < 4; ++i)
#pragma unroll
                    for (int j = 0; j < 4; ++j)
                        acc[i][j] = fmaf(pa[i], pb[j], acc[i][j]);
            }
            float* cp = ctx_out + base;
#pragma unroll
            for (int i = 0; i < 4; ++i)
                *(float4*)(cp + (h0 + i) * 64 + e0c) =
                    make_float4(acc[i][0], acc[i][1], acc[i][2], acc[i][3]);
        }
        LGKM0;   // phase-5 tile reads retired before next iter's phase-1 writes
    }
}

extern "C" void kernel_launch(void* const* d_in, const int* in_sizes, int n_in,
                              void* d_out, int out_size, void* d_ws, size_t ws_size,
                              hipStream_t stream) {
    const float* o0 = (const float*)d_in[0];
    const float* o1 = (const float*)d_in[1];
    const float* o2 = (const float*)d_in[2];
    const float* o3 = (const float*)d_in[3];
    const float* mn = (const float*)d_in[4];
    const float* W  = (const float*)d_in[5];
    float* ctx  = (float*)d_out;
    float* attn = ctx + (size_t)NBATCH * H * E;
    hipLaunchKernelGGL(ovo_kernel, dim3(NBLK), dim3(NWAVE * 64), 0, stream,
                       o0, o1, o2, o3, mn, W, ctx, attn);
}

// Round 9
// 88.588 us; speedup vs baseline: 1.0352x; 1.0352x over previous
//
#include <hip/hip_runtime.h>

#define NBATCH 16384
#define H 16
#define E 64
#define NB 4            // batches per wave
#define NWAVE 4         // waves per block
#define NBLK (NBATCH / (NB * NWAVE))   // 1024 blocks

typedef __attribute__((ext_vector_type(8))) short short8v;  // 8 bf16 = 4 VGPR
typedef __attribute__((ext_vector_type(4))) float f32x4;

// Cross-lane-through-LDS phase fence (rule #18): drain LDS pipe, block hoisting.
#define LGKM0 do { asm volatile("s_waitcnt lgkmcnt(0)" ::: "memory"); \
                   __builtin_amdgcn_sched_barrier(0); } while (0)

// Phase 2 (mean@W, 2/3 of all FLOPs) on the matrix cores:
//   mfma_f32_16x16x32_bf16, 2-term split (m=mhi+mlo, W=Whi+Wlo, 3 products)
//   -> fp32-class accuracy. A-frags built in registers from frag-ordered
//   global loads of the others; B-frags (W) pre-swizzled once per block into
//   LDS (bf16 hi/lo, 16KB), read as linear conflict-free ds_read_b128.
// Frag layouts (gfx950, 16x16x32 bf16):
//   A: lane L holds A[L&15][8*(L>>4)+i], i=0..7 (one b128 / short8v)
//   B: lane L holds B[8*(L>>4)+i][L&15]
//   D: lane L holds D[4*(L>>4)+j][L&15], j=0..3  [m89-verified]
// Phases 3-5 unchanged from R8 (fp32 VALU, proven accurate).
__global__ __launch_bounds__(256, 3) void ovo_kernel(
    const float* __restrict__ o0, const float* __restrict__ o1,
    const float* __restrict__ o2, const float* __restrict__ o3,
    const float* __restrict__ mn, const float* __restrict__ W,
    float* __restrict__ ctx_out, float* __restrict__ attn_out)
{
    // [t-tile][k-step][hi/lo][lane*8+i] : 4*2*2*512 ushort = 16KB
    __shared__ __align__(16) unsigned short sWfrag[4][2][2][512];
    __shared__ float sT[NWAVE][2][H * 68];   // per-wave: [0]=sU, [1]=sMain

    const int tid = threadIdx.x;
    const int l   = tid & 63;
    const int wv  = tid >> 6;

    // ---- One-time: W -> B-frag order, bf16 split (coalesced reads)
    for (int r = 0; r < 16; ++r) {
        const int flat = r * 256 + tid;
        const float w = W[flat];
        const int e = flat >> 6, f = flat & 63;
        const int t = f >> 4, col = f & 15;
        const int s = e >> 5, khi = (e >> 3) & 3, i = e & 7;
        const unsigned int wb = __float_as_uint(w);
        const unsigned int hb = wb & 0xFFFF0000u;
        const float lof = w - __uint_as_float(hb);
        const unsigned int lb = __float_as_uint(lof);
        const int L = col + 16 * khi;
        sWfrag[t][s][0][L * 8 + i] = (unsigned short)(hb >> 16);
        sWfrag[t][s][1][L * 8 + i] = (unsigned short)(lb >> 16);
    }
    __syncthreads();   // once per block; W-frags immutable afterwards

    float* const sU    = &sT[wv][0][0];   // mW (16x68) -> attnT (16x20) overlay
    float* const sMain = &sT[wv][1][0];   // main rows, stride 68

    const int q = l >> 4;    // k-oct / row-quad selector
    const int c = l & 15;

#pragma unroll 1
    for (int it = 0; it < NB; ++it) {
        const int batch = it * (NBLK * NWAVE) + blockIdx.x * NWAVE + wv;
        const size_t base = (size_t)batch * (H * E);

        // ---- Loads. m-inputs frag-ordered: lane l covers row (l&15),
        //      e = 32s + 8q + 4c01 .. +4 (all 128B lines fully covered by
        //      the instruction group). main linear-coalesced.
        float4 mo[2][2];   // mean sums per (s, c01)
#pragma unroll
        for (int s = 0; s < 2; ++s)
#pragma unroll
            for (int c01 = 0; c01 < 2; ++c01) {
                const size_t off = base + c * 64 + 32 * s + 8 * q + 4 * c01;
                float4 a = *(const float4*)(o0 + off);
                float4 b = *(const float4*)(o1 + off);
                float4 g = *(const float4*)(o2 + off);
                float4 d = *(const float4*)(o3 + off);
                mo[s][c01].x = (a.x + b.x) + (g.x + d.x);
                mo[s][c01].y = (a.y + b.y) + (g.y + d.y);
                mo[s][c01].z = (a.z + b.z) + (g.z + d.z);
                mo[s][c01].w = (a.w + b.w) + (g.w + d.w);
            }
        float4 rv[4];
#pragma unroll
        for (int k = 0; k < 4; ++k)
            rv[k] = *(const float4*)(mn + base + k * 256 + l * 4);

        // ---- main -> sMain (stride 68)
#pragma unroll
        for (int k = 0; k < 4; ++k) {
            const int flat = k * 256 + l * 4;
            *(float4*)&sMain[(flat >> 6) * 68 + (flat & 63)] = rv[k];
        }

        // ---- A-frags: mean*0.25 -> bf16 hi/lo split, packed in regs
        short8v ahi[2], alo[2];
#pragma unroll
        for (int s = 0; s < 2; ++s) {
            float ms[8];
            ms[0] = mo[s][0].x; ms[1] = mo[s][0].y; ms[2] = mo[s][0].z; ms[3] = mo[s][0].w;
            ms[4] = mo[s][1].x; ms[5] = mo[s][1].y; ms[6] = mo[s][1].z; ms[7] = mo[s][1].w;
#pragma unroll
            for (int i = 0; i < 8; ++i) {
                const float m = ms[i] * 0.25f;
                const unsigned int mb = __float_as_uint(m);
                const unsigned int hb = mb & 0xFFFF0000u;
                const float lof = m - __uint_as_float(hb);
                ahi[s][i] = (short)(hb >> 16);
                alo[s][i] = (short)(__float_as_uint(lof) >> 16);
            }
        }

        // ---- Phase 2 MFMA: mW = m @ W  (4 f-tiles x 2 k-steps x 3 products)
#pragma unroll
        for (int t = 0; t < 4; ++t) {
            short8v bh0 = *(const short8v*)&sWfrag[t][0][0][l * 8];
            short8v bl0 = *(const short8v*)&sWfrag[t][0][1][l * 8];
            short8v bh1 = *(const short8v*)&sWfrag[t][1][0][l * 8];
            short8v bl1 = *(const short8v*)&sWfrag[t][1][1][l * 8];
            f32x4 acc = {0.f, 0.f, 0.f, 0.f};
            acc = __builtin_amdgcn_mfma_f32_16x16x32_bf16(ahi[0], bh0, acc, 0, 0, 0);
            acc = __builtin_amdgcn_mfma_f32_16x16x32_bf16(alo[0], bh0, acc, 0, 0, 0);
            acc = __builtin_amdgcn_mfma_f32_16x16x32_bf16(ahi[0], bl0, acc, 0, 0, 0);
            acc = __builtin_amdgcn_mfma_f32_16x16x32_bf16(ahi[1], bh1, acc, 0, 0, 0);
            acc = __builtin_amdgcn_mfma_f32_16x16x32_bf16(alo[1], bh1, acc, 0, 0, 0);
            acc = __builtin_amdgcn_mfma_f32_16x16x32_bf16(ahi[1], bl1, acc, 0, 0, 0);
            // D: lane holds mW[4q+j][16t+c] -> union LDS (2-way banks, free)
#pragma unroll
            for (int j = 0; j < 4; ++j)
                sU[(4 * q + j) * 68 + 16 * t + c] = acc[j];
        }
        LGKM0;   // sMain + mW visible to all lanes

        // ---- Phase 3: score[hp][g0..g0+3] in registers. lane = hp*4+gp.
        const int hp = l >> 2, gp = l & 3;
        const int g0 = gp * 4;
        float scr[4] = {0.f, 0.f, 0.f, 0.f};
#pragma unroll
        for (int f0 = 0; f0 < 64; f0 += 4) {
            float4 a0 = *(const float4*)&sU[hp * 68 + f0];      // bcast x4
            const float* pa = (const float*)&a0;
            float4 b[4];
#pragma unroll
            for (int j = 0; j < 4; ++j)
                b[j] = *(const float4*)&sMain[(g0 + j) * 68 + f0];  // bcast x16
#pragma unroll
            for (int j = 0; j < 4; ++j) {
                const float* pb = (const float*)&b[j];
#pragma unroll
                for (int u = 0; u < 4; ++u)
                    scr[j] = fmaf(pa[u], pb[u], scr[j]);
            }
        }

        // ---- Phase 4: quad softmax over row hp (4 gp lanes x 4 values)
        {
            float mx = fmaxf(fmaxf(scr[0], scr[1]), fmaxf(scr[2], scr[3]));
            mx = fmaxf(mx, __shfl_xor(mx, 1));
            mx = fmaxf(mx, __shfl_xor(mx, 2));
            float e0 = __expf(scr[0] - mx), e1 = __expf(scr[1] - mx);
            float e2 = __expf(scr[2] - mx), e3 = __expf(scr[3] - mx);
            float sum = (e0 + e1) + (e2 + e3);
            sum += __shfl_xor(sum, 1);
            sum += __shfl_xor(sum, 2);
            const float inv = 1.0f / sum;
            float4 a4 = make_float4(e0 * inv, e1 * inv, e2 * inv, e3 * inv);
            // coalesced 1KB attn store
            *(float4*)(attn_out + (size_t)batch * (H * H) + l * 4) = a4;
            // attn^T into sU overlay (stride 20; mW dead after phase 3)
            const float* pa4 = (const float*)&a4;
#pragma unroll
            for (int j = 0; j < 4; ++j)
                sU[(g0 + j) * 20 + hp] = pa4[j];
        }
        LGKM0;   // attnT visible to all lanes

        // ---- Phase 5: context[h][e] = sum_g attn[h][g]*main[g][e]
        {
            const int ht = q, et = c;
            const int h0 = ht * 4, e0c = et * 4;
            f32x4 acc2[4] = {{0.f,0.f,0.f,0.f},{0.f,0.f,0.f,0.f},
                             {0.f,0.f,0.f,0.f},{0.f,0.f,0.f,0.f}};
#pragma unroll
            for (int g = 0; g < 16; ++g) {
                float4 bv = *(const float4*)&sMain[g * 68 + e0c];
                float4 av = *(const float4*)&sU[g * 20 + h0];   // attnT
                const float* pb = (const float*)&bv;
                const float* pa = (const float*)&av;
#pragma unroll
                for (int i = 0; i < 4; ++i)
#pragma unroll
                    for (int j = 0; j < 4; ++j)
                        acc2[i][j] = fmaf(pa[i], pb[j], acc2[i][j]);
            }
            float* cp = ctx_out + base;
#pragma unroll
            for (int i = 0; i < 4; ++i)
                *(float4*)(cp + (h0 + i) * 64 + e0c) =
                    make_float4(acc2[i][0], acc2[i][1], acc2[i][2], acc2[i][3]);
        }
        // no fence: next iter's LDS writes can't pass p5 reads (same-wave
        // in-order DS + compiler alias on the same __shared__ arrays)
    }
}

extern "C" void kernel_launch(void* const* d_in, const int* in_sizes, int n_in,
                              void* d_out, int out_size, void* d_ws, size_t ws_size,
                              hipStream_t stream) {
    const float* o0 = (const float*)d_in[0];
    const float* o1 = (const float*)d_in[1];
    const float* o2 = (const float*)d_in[2];
    const float* o3 = (const float*)d_in[3];
    const float* mn = (const float*)d_in[4];
    const float* W  = (const float*)d_in[5];
    float* ctx  = (float*)d_out;
    float* attn = ctx + (size_t)NBATCH * H * E;
    hipLaunchKernelGGL(ovo_kernel, dim3(NBLK), dim3(NWAVE * 64), 0, stream,
                       o0, o1, o2, o3, mn, W, ctx, attn);
}